// Round 1
// baseline (8165.556 us; speedup 1.0000x reference)
//
#include <hip/hip_runtime.h>
#include <cstddef>

// ---- problem constants ----
constexpr int kN   = 16;
constexpr int kI   = 128;
constexpr int kR   = 256;
constexpr int kA   = 256;
constexpr int kHEADS = 8;
constexpr int kHC  = 32;
constexpr int kHW  = 24;
constexpr int kQ   = 576;          // 24*24
constexpr int kHV  = 22;
constexpr int kD   = 484;          // 22*22
constexpr int kPP  = 676;          // 26*26 padded image
constexpr int kDCH = 121;          // attention d-chunk (484 = 4*121)

// ---- workspace layout (floats) ----
constexpr size_t OFF_XINPAD = 0;
constexpr size_t SZ_PAD     = (size_t)kN * kR * kPP;           // 2,768,896
constexpr size_t OFF_H0PAD  = OFF_XINPAD + SZ_PAD;
constexpr size_t OFF_Q      = OFF_H0PAD + SZ_PAD;
constexpr size_t SZ_Q       = (size_t)kN * kA * kQ;            // 2,359,296
constexpr size_t OFF_K      = OFF_Q + SZ_Q;
constexpr size_t SZ_KV      = (size_t)kN * kA * kD;            // 1,982,464
constexpr size_t OFF_V      = OFF_K + SZ_KV;
constexpr size_t OFF_ATT    = OFF_V + SZ_KV;
constexpr size_t OFF_G      = OFF_ATT + SZ_Q;
constexpr size_t SZ_G       = (size_t)kN * 4 * kR * kQ;        // 9,437,184
constexpr size_t OFF_H      = OFF_G + SZ_G;

__device__ __forceinline__ float sigm(float x) { return 1.0f / (1.0f + __expf(-x)); }
__device__ __forceinline__ float tanh_f(float x) {
    float e = __expf(2.0f * fabsf(x));
    float r = 1.0f - 2.0f / (e + 1.0f);   // e==inf -> r==1
    return copysignf(r, x);
}

// h0 [N,R,24,24] -> padded [N,R,26,26] with zero border
__global__ void pad_copy_kernel(const float* __restrict__ src, float* __restrict__ dst) {
    int idx = blockIdx.x * 256 + threadIdx.x;           // exactly N*R*PP threads
    int ch = idx / kPP, cell = idx % kPP;
    int r = cell / 26, c = cell % 26;
    bool inter = (r >= 1 && r <= 24 && c >= 1 && c <= 24);
    int rr = min(max(r - 1, 0), 23), cc = min(max(c - 1, 0), 23);
    float v = src[(size_t)ch * kQ + rr * 24 + cc];
    dst[idx] = inter ? v : 0.0f;
}

// 1x1 conv: out[n,oc,px] = bias[oc] + sum_ic w[oc,ic]*in[n,ic,px]
// block (64,4): lanes = px, 4 oc per thread (16 oc per block)
template<bool PADOUT>
__global__ void conv1x1_kernel(const float* __restrict__ in, const float* __restrict__ w,
                               const float* __restrict__ bias, float* __restrict__ out,
                               int IC, int OC) {
    int px = blockIdx.x * 64 + threadIdx.x;
    int n  = blockIdx.z;
    int oc0 = __builtin_amdgcn_readfirstlane(blockIdx.y * 16 + threadIdx.y * 4);
    const float* ip = in + (size_t)n * IC * kQ + px;
    float acc[4] = {0.f, 0.f, 0.f, 0.f};
    #pragma unroll 4
    for (int ic = 0; ic < IC; ++ic) {
        float xv = ip[(size_t)ic * kQ];
        #pragma unroll
        for (int j = 0; j < 4; ++j) acc[j] = fmaf(xv, w[(size_t)(oc0 + j) * IC + ic], acc[j]);
    }
    int y = px / kHW, xcol = px % kHW;
    #pragma unroll
    for (int j = 0; j < 4; ++j) {
        float r = acc[j];
        if (bias) r += bias[oc0 + j];
        if (PADOUT)
            out[((size_t)n * OC + oc0 + j) * kPP + (y + 1) * 26 + (xcol + 1)] = r;
        else
            out[((size_t)n * OC + oc0 + j) * kQ + px] = r;
    }
}

// dual 3x3 conv (+optional 1x1 third input) from padded inputs (pitch 26)
// SAME: out 24x24 ; VALID: out 22x22
template<bool SAME, bool HAS3>
__global__ void conv3x3_dual_kernel(const float* __restrict__ in1p, const float* __restrict__ in2p,
                                    const float* __restrict__ w1, const float* __restrict__ w2,
                                    const float* __restrict__ in3, const float* __restrict__ w3,
                                    const float* __restrict__ bias, float* __restrict__ out, int OC) {
    constexpr int OW  = SAME ? 24 : 22;
    constexpr int OPX = OW * OW;
    int px   = blockIdx.x * 64 + threadIdx.x;
    bool live = SAME ? true : (px < OPX);
    int pxc  = SAME ? px : min(px, OPX - 1);
    int oy = pxc / OW, ox = pxc % OW;
    int base = SAME ? (oy * 26 + ox) : ((oy + 1) * 26 + (ox + 1));
    int oc0 = __builtin_amdgcn_readfirstlane(blockIdx.y * 16 + threadIdx.y * 4);
    int n = blockIdx.z;
    const float* i1 = in1p + (size_t)n * kR * kPP + base;
    const float* i2 = in2p + (size_t)n * kR * kPP + base;
    const float* i3 = HAS3 ? (in3 + (size_t)n * kR * kQ + pxc) : nullptr;
    float acc[4] = {0.f, 0.f, 0.f, 0.f};
    for (int ic = 0; ic < kR; ++ic) {
        float v[9];
        #pragma unroll
        for (int t = 0; t < 9; ++t) v[t] = i1[(size_t)ic * kPP + (t / 3) * 26 + (t % 3)];
        #pragma unroll
        for (int j = 0; j < 4; ++j) {
            const float* wp = w1 + ((size_t)(oc0 + j) * kR + ic) * 9;
            #pragma unroll
            for (int t = 0; t < 9; ++t) acc[j] = fmaf(v[t], wp[t], acc[j]);
        }
        #pragma unroll
        for (int t = 0; t < 9; ++t) v[t] = i2[(size_t)ic * kPP + (t / 3) * 26 + (t % 3)];
        #pragma unroll
        for (int j = 0; j < 4; ++j) {
            const float* wp = w2 + ((size_t)(oc0 + j) * kR + ic) * 9;
            #pragma unroll
            for (int t = 0; t < 9; ++t) acc[j] = fmaf(v[t], wp[t], acc[j]);
        }
        if (HAS3) {
            float av = i3[(size_t)ic * kQ];
            #pragma unroll
            for (int j = 0; j < 4; ++j) acc[j] = fmaf(av, w3[(size_t)(oc0 + j) * kR + ic], acc[j]);
        }
    }
    if (live) {
        #pragma unroll
        for (int j = 0; j < 4; ++j) {
            float r = acc[j];
            if (bias) r += bias[oc0 + j];
            out[((size_t)n * OC + oc0 + j) * OPX + pxc] = r;
        }
    }
}

// attention: per (n,head): S = q^T k [576,484], softmax over d, a = v @ w^T
// grid (3, N*HEADS), block 192: 1 q-row per thread; k,v chunks [d][32] in LDS
__global__ __launch_bounds__(192)
void attn_kernel(const float* __restrict__ qb, const float* __restrict__ kb,
                 const float* __restrict__ vb, float* __restrict__ ab) {
    __shared__ float ks[kDCH * 32];
    __shared__ float vs[kDCH * 32];
    int n  = blockIdx.y >> 3;
    int hd = blockIdx.y & 7;
    const float* qp = qb + ((size_t)n * kA + hd * kHC) * kQ;
    const float* kp = kb + ((size_t)n * kA + hd * kHC) * kD;
    const float* vp = vb + ((size_t)n * kA + hd * kHC) * kD;
    float* ap = ab + ((size_t)n * kA + hd * kHC) * kQ;
    int row = blockIdx.x * 192 + threadIdx.x;   // 0..575

    float qv[32], acc[32];
    #pragma unroll
    for (int j = 0; j < 32; ++j) { qv[j] = qp[(size_t)j * kQ + row]; acc[j] = 0.f; }
    float m = -1e30f, l = 0.f;

    for (int c0 = 0; c0 < kD; c0 += kDCH) {
        __syncthreads();
        for (int t = threadIdx.x; t < kDCH * 32; t += 192) {
            int j = t / kDCH, d = t % kDCH;
            ks[d * 32 + j] = kp[(size_t)j * kD + c0 + d];
            vs[d * 32 + j] = vp[(size_t)j * kD + c0 + d];
        }
        __syncthreads();
        // pass 1: chunk max
        float ml = -1e30f;
        for (int d = 0; d < kDCH; ++d) {
            const float4* k4 = reinterpret_cast<const float4*>(ks) + d * 8;
            float s = 0.f;
            #pragma unroll
            for (int g = 0; g < 8; ++g) {
                float4 kvv = k4[g];
                s = fmaf(qv[4*g+0], kvv.x, s); s = fmaf(qv[4*g+1], kvv.y, s);
                s = fmaf(qv[4*g+2], kvv.z, s); s = fmaf(qv[4*g+3], kvv.w, s);
            }
            ml = fmaxf(ml, s);
        }
        float mn = fmaxf(m, ml);
        float f = __expf(m - mn);
        l *= f;
        #pragma unroll
        for (int j = 0; j < 32; ++j) acc[j] *= f;
        m = mn;
        // pass 2: accumulate exp * v
        for (int d = 0; d < kDCH; ++d) {
            const float4* k4 = reinterpret_cast<const float4*>(ks) + d * 8;
            float s = 0.f;
            #pragma unroll
            for (int g = 0; g < 8; ++g) {
                float4 kvv = k4[g];
                s = fmaf(qv[4*g+0], kvv.x, s); s = fmaf(qv[4*g+1], kvv.y, s);
                s = fmaf(qv[4*g+2], kvv.z, s); s = fmaf(qv[4*g+3], kvv.w, s);
            }
            float p = __expf(s - m);
            l += p;
            const float4* v4 = reinterpret_cast<const float4*>(vs) + d * 8;
            #pragma unroll
            for (int g = 0; g < 8; ++g) {
                float4 vv = v4[g];
                acc[4*g+0] = fmaf(p, vv.x, acc[4*g+0]); acc[4*g+1] = fmaf(p, vv.y, acc[4*g+1]);
                acc[4*g+2] = fmaf(p, vv.z, acc[4*g+2]); acc[4*g+3] = fmaf(p, vv.w, acc[4*g+3]);
            }
        }
    }
    float inv = 1.f / l;
    #pragma unroll
    for (int j = 0; j < 32; ++j) ap[(size_t)j * kQ + row] = acc[j] * inv;
}

// gates [N,4R,Q] + c0 -> h [N,R,Q]
__global__ void lstm_kernel(const float* __restrict__ gates, const float* __restrict__ c0,
                            float* __restrict__ h) {
    int idx = blockIdx.x * 256 + threadIdx.x;           // N*R*Q threads exactly
    int n  = idx / (kR * kQ);
    int rq = idx % (kR * kQ);
    const float* gb = gates + (size_t)n * (4 * kR * kQ) + rq;
    float iv = gb[0];
    float fv = gb[(size_t)kR * kQ];
    float gv = gb[(size_t)2 * kR * kQ];
    float ov = gb[(size_t)3 * kR * kQ];
    float c = sigm(fv) * c0[idx] + sigm(iv) * tanh_f(gv);
    h[idx] = sigm(ov) * tanh_f(c);
}

extern "C" void kernel_launch(void* const* d_in, const int* in_sizes, int n_in,
                              void* d_out, int out_size, void* d_ws, size_t ws_size,
                              hipStream_t stream) {
    const float* x     = (const float*)d_in[0];
    const float* h0    = (const float*)d_in[1];
    const float* c0    = (const float*)d_in[2];
    const float* w_in  = (const float*)d_in[3];
    const float* b_in  = (const float*)d_in[4];
    const float* wq_x  = (const float*)d_in[5];
    const float* wq_h  = (const float*)d_in[6];
    const float* wk_x  = (const float*)d_in[7];
    const float* wk_h  = (const float*)d_in[8];
    const float* wv_x  = (const float*)d_in[9];
    const float* wv_h  = (const float*)d_in[10];
    const float* bv    = (const float*)d_in[11];
    const float* wg_a  = (const float*)d_in[12];
    const float* bg    = (const float*)d_in[13];
    const float* wg_x  = (const float*)d_in[14];
    const float* wg_h  = (const float*)d_in[15];
    const float* w_out = (const float*)d_in[16];
    const float* b_out = (const float*)d_in[17];

    float* ws      = (float*)d_ws;
    float* xin_pad = ws + OFF_XINPAD;
    float* h0_pad  = ws + OFF_H0PAD;
    float* qbuf    = ws + OFF_Q;
    float* kbuf    = ws + OFF_K;
    float* vbuf    = ws + OFF_V;
    float* abuf    = ws + OFF_ATT;
    float* gbuf    = ws + OFF_G;
    float* hbuf    = ws + OFF_H;

    dim3 blk(64, 4);

    // stage padded inputs (ws is re-poisoned each launch -> borders must be zeroed every call)
    hipMemsetAsync(xin_pad, 0, SZ_PAD * sizeof(float), stream);
    pad_copy_kernel<<<(int)(SZ_PAD / 256), 256, 0, stream>>>(h0, h0_pad);

    // xin = 1x1(x, w_in) + b_in  -> padded
    conv1x1_kernel<true><<<dim3(9, 16, kN), blk, 0, stream>>>(x, w_in, b_in, xin_pad, kI, kR);

    // q (SAME), k/v (VALID)
    conv3x3_dual_kernel<true,  false><<<dim3(9, 16, kN), blk, 0, stream>>>(
        xin_pad, h0_pad, wq_x, wq_h, nullptr, nullptr, nullptr, qbuf, kA);
    conv3x3_dual_kernel<false, false><<<dim3(8, 16, kN), blk, 0, stream>>>(
        xin_pad, h0_pad, wk_x, wk_h, nullptr, nullptr, nullptr, kbuf, kA);
    conv3x3_dual_kernel<false, false><<<dim3(8, 16, kN), blk, 0, stream>>>(
        xin_pad, h0_pad, wv_x, wv_h, nullptr, nullptr, bv, vbuf, kA);

    // attention -> abuf
    attn_kernel<<<dim3(3, kN * kHEADS), 192, 0, stream>>>(qbuf, kbuf, vbuf, abuf);

    // gates = 1x1(a, wg_a) + bg + 3x3 SAME(xin, wg_x) + 3x3 SAME(h0, wg_h)
    conv3x3_dual_kernel<true, true><<<dim3(9, 64, kN), blk, 0, stream>>>(
        xin_pad, h0_pad, wg_x, wg_h, abuf, wg_a, bg, gbuf, 4 * kR);

    // LSTM elementwise -> h
    lstm_kernel<<<(int)((size_t)kN * kR * kQ / 256), 256, 0, stream>>>(gbuf, c0, hbuf);

    // out = 1x1(h, w_out) + b_out
    conv1x1_kernel<false><<<dim3(9, 16, kN), blk, 0, stream>>>(hbuf, w_out, b_out, (float*)d_out, kR, kR);
}

// Round 2
// 1549.061 us; speedup vs baseline: 5.2713x; 5.2713x over previous
//
#include <hip/hip_runtime.h>
#include <cstddef>

// ---- problem constants ----
constexpr int kN  = 16;
constexpr int kI  = 128;
constexpr int kR  = 256;
constexpr int kHW = 24;
constexpr int kQ  = 576;    // 24*24
constexpr int kD  = 484;    // 22*22
constexpr int kPP = 676;    // 26*26 padded

// GEMM shapes
constexpr int kM1 = 1792, kKT1 = 144;   // K1 = 4608
constexpr int kM2 = 1024, kKT2 = 8;     // K2 = 256
constexpr int kM3 = 256,  kKT3 = 8;     // K3 = 256

// ---- workspace layout ----
// half region (element offsets into _Float16*)
constexpr size_t H_XPAD   = 0;                          // [16][256][676]
constexpr size_t H_HPAD   = 2768896;                    // [16][256][676]
constexpr size_t H_APACK1 = 5537792;                    // 1792*4608 tiled
constexpr size_t H_APACK2 = 13795328;                   // 1024*256 tiled
constexpr size_t H_APACK3 = 14057472;                   // 256*256 tiled
constexpr size_t H_A16    = 14123008;                   // [16][576][256]
constexpr size_t H_H16    = 16482304;                   // [16][576][256]
constexpr size_t HALF_BYTES = 37683200;                 // 18,841,600 halves
// float region (element offsets into float* at d_ws + HALF_BYTES)
constexpr size_t F_Q  = 0;            // [16][256][576]
constexpr size_t F_KT = 2359296;      // [16][8][484][32]
constexpr size_t F_VT = 4341760;      // [16][8][484][32]
constexpr size_t F_G  = 6324224;      // [16][1024][576]

using half4    = __attribute__((ext_vector_type(4))) _Float16;
using half8    = __attribute__((ext_vector_type(8))) _Float16;
using floatx16 = __attribute__((ext_vector_type(16))) float;

__device__ __forceinline__ float sigm(float x) { return 1.0f / (1.0f + __expf(-x)); }
__device__ __forceinline__ float tanh_f(float x) {
    float e = __expf(2.0f * fabsf(x));
    float r = 1.0f - 2.0f / (e + 1.0f);
    return copysignf(r, x);
}

__device__ __forceinline__ half8 ld8(const _Float16* p) {
    half4 lo = *(const half4*)p;
    half4 hi = *(const half4*)(p + 4);
    return __builtin_shufflevector(lo, hi, 0, 1, 2, 3, 4, 5, 6, 7);
}
__device__ __forceinline__ void st8(_Float16* p, half8 v) {
    *(half4*)p       = __builtin_shufflevector(v, v, 0, 1, 2, 3);
    *(half4*)(p + 4) = __builtin_shufflevector(v, v, 4, 5, 6, 7);
}

// ---------------- weight packing ----------------
// Apack layout: [mt][kt][128 rows][32 k] contiguous 4096-half tiles.
__global__ void pack1_kernel(const float* __restrict__ wq_x, const float* __restrict__ wq_h,
                             const float* __restrict__ wk_x, const float* __restrict__ wk_h,
                             const float* __restrict__ wv_x, const float* __restrict__ wv_h,
                             const float* __restrict__ wg_x, const float* __restrict__ wg_h,
                             _Float16* __restrict__ dst) {
    int pidx = blockIdx.x * 256 + threadIdx.x;
    int kcol = pidx & 31, mrow = (pidx >> 5) & 127, tile = pidx >> 12;
    int mt = tile / kKT1, kt = tile - mt * kKT1;
    int m = mt * 128 + mrow, k = kt * 32 + kcol;
    const float *s1, *s2; int mm;
    if (m < 256)      { s1 = wq_x; s2 = wq_h; mm = m; }
    else if (m < 512) { s1 = wk_x; s2 = wk_h; mm = m - 256; }
    else if (m < 768) { s1 = wv_x; s2 = wv_h; mm = m - 512; }
    else              { s1 = wg_x; s2 = wg_h; mm = m - 768; }
    float v = (k < 2304) ? s1[(size_t)mm * 2304 + k] : s2[(size_t)mm * 2304 + k - 2304];
    dst[pidx] = (_Float16)v;
}

__global__ void pack_flat_kernel(const float* __restrict__ src, _Float16* __restrict__ dst,
                                 int Ktot, int Ktiles) {
    int pidx = blockIdx.x * 256 + threadIdx.x;
    int kcol = pidx & 31, mrow = (pidx >> 5) & 127, tile = pidx >> 12;
    int mt = tile / Ktiles, kt = tile - mt * Ktiles;
    dst[pidx] = (_Float16)src[(size_t)(mt * 128 + mrow) * Ktot + kt * 32 + kcol];
}

// ---------------- input staging ----------------
// h0 [16*256][576] fp32 -> fp16 padded [16*256][676] interior (borders pre-zeroed)
__global__ void padcvt_kernel(const float* __restrict__ src, _Float16* __restrict__ dst) {
    int idx = blockIdx.x * 256 + threadIdx.x;    // 16*256*576 exactly
    int ch = idx / kQ, px = idx - ch * kQ;
    int y = px / kHW, x = px - y * kHW;
    dst[(size_t)ch * kPP + (y + 1) * 26 + (x + 1)] = (_Float16)src[idx];
}

// xin = 1x1 conv(x, w_in)+b_in -> fp16 padded
__global__ void conv1x1_pad_kernel(const float* __restrict__ x, const float* __restrict__ w,
                                   const float* __restrict__ b, _Float16* __restrict__ out) {
    int px = blockIdx.x * 64 + threadIdx.x;
    int n = blockIdx.z;
    int oc0 = __builtin_amdgcn_readfirstlane(blockIdx.y * 16 + threadIdx.y * 4);
    const float* ip = x + (size_t)n * kI * kQ + px;
    float acc[4] = {0.f, 0.f, 0.f, 0.f};
    #pragma unroll 4
    for (int ic = 0; ic < kI; ++ic) {
        float xv = ip[(size_t)ic * kQ];
        #pragma unroll
        for (int j = 0; j < 4; ++j) acc[j] = fmaf(xv, w[(size_t)(oc0 + j) * kI + ic], acc[j]);
    }
    int y = px / kHW, xc = px - y * kHW;
    #pragma unroll
    for (int j = 0; j < 4; ++j)
        out[((size_t)n * 256 + oc0 + j) * kPP + (y + 1) * 26 + (xc + 1)] = (_Float16)(acc[j] + b[oc0 + j]);
}

// ---------------- fused MFMA GEMM ----------------
// BM=128, BN=64, BK=32; 256 threads = 4 waves; wave w: rows [w*32,w*32+32) x all 64 cols.
// BMODE 0: B = on-the-fly im2col from two padded fp16 images (K=4608: src,ic,tap)
// BMODE 1: B = direct [n][576][Ktot] fp16
// EMODE 0: rows 0..255->q fp32 [n][256][576]; 256..511->kT; 512..767->vT(+bias=bv)
//          (interior px only, [n][8][484][32]); 768..1791->g3 [n][1024][576]
// EMODE 1: gates += : p3[idx] = acc + p3[idx] + bias[m]
// EMODE 2: out = acc + bias[m] -> p0 [n][256][576]
template<int BMODE, int EMODE>
__global__ __launch_bounds__(256)
void gemm_kernel(const _Float16* __restrict__ Apack,
                 const _Float16* __restrict__ B1, const _Float16* __restrict__ B2,
                 float* __restrict__ p0, float* __restrict__ p1,
                 float* __restrict__ p2, float* __restrict__ p3,
                 const float* __restrict__ bias, int Ktiles, int Ktot) {
    __shared__ _Float16 As[128 * 36];
    __shared__ _Float16 Bs[64 * 36];
    const int tid = threadIdx.x;
    const int wv = tid >> 6, lane = tid & 63, l31 = lane & 31, hl = lane >> 5;
    const int mt = blockIdx.x, nt = blockIdx.y, n = blockIdx.z;

    floatx16 acc0 = {};
    floatx16 acc1 = {};

    const size_t Abase = (size_t)mt * Ktiles * 4096;
    const int arow = tid >> 1, ak = (tid & 1) * 16;
    const int px_l = tid >> 2, bg4 = (tid & 3) * 8;
    const int px = nt * 64 + px_l;
    const int by = px / kHW, bx = px - by * kHW;

    for (int kt = 0; kt < Ktiles; ++kt) {
        // stage A (packed tiles are contiguous 8KB; coalesced 32B/thread)
        half8 a0 = *(const half8*)(Apack + Abase + (size_t)kt * 4096 + tid * 16);
        half8 a1 = *(const half8*)(Apack + Abase + (size_t)kt * 4096 + tid * 16 + 8);
        // stage B
        half8 bvv;
        if (BMODE == 0) {
            int kbase = kt * 32 + bg4;
            #pragma unroll
            for (int j = 0; j < 8; ++j) {
                int k = kbase + j;
                const _Float16* img = (k < 2304) ? B1 : B2;
                unsigned k2 = (k < 2304) ? k : k - 2304;
                unsigned ic = k2 / 9u;
                unsigned tap = k2 - ic * 9u;
                unsigned ty = tap / 3u, tx = tap - ty * 3u;
                bvv[j] = img[((size_t)n * 256 + ic) * kPP + (by + ty) * 26 + (bx + tx)];
            }
        } else {
            bvv = *(const half8*)(B1 + ((size_t)n * kQ + px) * Ktot + kt * 32 + bg4);
        }
        st8(&As[arow * 36 + ak], a0);
        st8(&As[arow * 36 + ak + 8], a1);
        st8(&Bs[px_l * 36 + bg4], bvv);
        __syncthreads();
        #pragma unroll
        for (int kk = 0; kk < 2; ++kk) {
            half8 af = ld8(&As[(wv * 32 + l31) * 36 + kk * 16 + hl * 8]);
            half8 b0 = ld8(&Bs[l31 * 36 + kk * 16 + hl * 8]);
            half8 b1 = ld8(&Bs[(32 + l31) * 36 + kk * 16 + hl * 8]);
            acc0 = __builtin_amdgcn_mfma_f32_32x32x16_f16(af, b0, acc0, 0, 0, 0);
            acc1 = __builtin_amdgcn_mfma_f32_32x32x16_f16(af, b1, acc1, 0, 0, 0);
        }
        __syncthreads();
    }

    // epilogue: C/D layout col=lane&31, row=(reg&3)+8*(reg>>2)+4*(lane>>5)
    const int mbase = mt * 128 + wv * 32;
    #pragma unroll
    for (int t2 = 0; t2 < 2; ++t2) {
        const floatx16& A = t2 ? acc1 : acc0;
        int pxe = nt * 64 + t2 * 32 + l31;
        #pragma unroll
        for (int r = 0; r < 16; ++r) {
            int rowi = (r & 3) + 8 * (r >> 2) + 4 * hl;
            int m = mbase + rowi;
            float val = A[r];
            if (EMODE == 0) {
                if (m < 256) {
                    p0[((size_t)n * 256 + m) * kQ + pxe] = val;
                } else if (m < 768) {
                    int ch = m & 255;
                    int yy = pxe / kHW, xx = pxe - yy * kHW;
                    if (yy >= 1 && yy <= 22 && xx >= 1 && xx <= 22) {
                        int d = (yy - 1) * 22 + (xx - 1);
                        float bb = (m < 512) ? 0.f : bias[ch];
                        float* dst = (m < 512) ? p1 : p2;
                        dst[(((size_t)n * 8 + (ch >> 5)) * kD + d) * 32 + (ch & 31)] = val + bb;
                    }
                } else {
                    p3[((size_t)n * 1024 + (m - 768)) * kQ + pxe] = val;
                }
            } else if (EMODE == 1) {
                size_t o = ((size_t)n * 1024 + m) * kQ + pxe;
                p3[o] = val + p3[o] + bias[m];
            } else {
                p0[((size_t)n * 256 + m) * kQ + pxe] = val + bias[m];
            }
        }
    }
}

// ---------------- attention ----------------
// grid (9, 128), block 64 (1 wave). thread = one q row. kT/vT rows are
// wave-uniform -> scalar-load broadcast, no LDS. Two-pass online softmax.
__global__ __launch_bounds__(64)
void attn_kernel(const float* __restrict__ qbuf, const float* __restrict__ kT,
                 const float* __restrict__ vT, _Float16* __restrict__ a16) {
    int lane = threadIdx.x;
    int row = blockIdx.x * 64 + lane;
    int hd = blockIdx.y & 7, n = blockIdx.y >> 3;
    const float* qp = qbuf + ((size_t)n * 256 + hd * 32) * kQ + row;
    float qv[32];
    #pragma unroll
    for (int j = 0; j < 32; ++j) qv[j] = qp[(size_t)j * kQ];
    const float* kp = kT + ((size_t)n * 8 + hd) * kD * 32;
    const float* vp = vT + ((size_t)n * 8 + hd) * kD * 32;

    float mx = -1e30f;
    for (int d = 0; d < kD; ++d) {
        const float* kd = kp + d * 32;
        float s = 0.f;
        #pragma unroll
        for (int j = 0; j < 32; ++j) s = fmaf(qv[j], kd[j], s);
        mx = fmaxf(mx, s);
    }
    float l = 0.f, acc[32];
    #pragma unroll
    for (int j = 0; j < 32; ++j) acc[j] = 0.f;
    for (int d = 0; d < kD; ++d) {
        const float* kd = kp + d * 32;
        const float* vd = vp + d * 32;
        float s = 0.f;
        #pragma unroll
        for (int j = 0; j < 32; ++j) s = fmaf(qv[j], kd[j], s);
        float p = __expf(s - mx);
        l += p;
        #pragma unroll
        for (int j = 0; j < 32; ++j) acc[j] = fmaf(p, vd[j], acc[j]);
    }
    float inv = 1.f / l;
    _Float16* ap = a16 + ((size_t)n * kQ + row) * 256 + hd * 32;
    #pragma unroll
    for (int j = 0; j < 32; ++j) ap[j] = (_Float16)(acc[j] * inv);
}

// ---------------- LSTM elementwise ----------------
__global__ void lstm_kernel(const float* __restrict__ gates, const float* __restrict__ c0,
                            _Float16* __restrict__ h16) {
    int px = blockIdx.x * 64 + threadIdx.x;
    int r = blockIdx.y * 4 + threadIdx.y;
    int n = blockIdx.z;
    size_t base = (size_t)n * 1024 * kQ + px;
    float iv = gates[base + (size_t)r * kQ];
    float fv = gates[base + (size_t)(256 + r) * kQ];
    float gv = gates[base + (size_t)(512 + r) * kQ];
    float ov = gates[base + (size_t)(768 + r) * kQ];
    float c = sigm(fv) * c0[((size_t)n * 256 + r) * kQ + px] + sigm(iv) * tanh_f(gv);
    float h = sigm(ov) * tanh_f(c);
    h16[((size_t)n * kQ + px) * 256 + r] = (_Float16)h;
}

extern "C" void kernel_launch(void* const* d_in, const int* in_sizes, int n_in,
                              void* d_out, int out_size, void* d_ws, size_t ws_size,
                              hipStream_t stream) {
    (void)in_sizes; (void)n_in; (void)out_size; (void)ws_size;
    const float* x     = (const float*)d_in[0];
    const float* h0    = (const float*)d_in[1];
    const float* c0    = (const float*)d_in[2];
    const float* w_in  = (const float*)d_in[3];
    const float* b_in  = (const float*)d_in[4];
    const float* wq_x  = (const float*)d_in[5];
    const float* wq_h  = (const float*)d_in[6];
    const float* wk_x  = (const float*)d_in[7];
    const float* wk_h  = (const float*)d_in[8];
    const float* wv_x  = (const float*)d_in[9];
    const float* wv_h  = (const float*)d_in[10];
    const float* bv    = (const float*)d_in[11];
    const float* wg_a  = (const float*)d_in[12];
    const float* bg    = (const float*)d_in[13];
    const float* wg_x  = (const float*)d_in[14];
    const float* wg_h  = (const float*)d_in[15];
    const float* w_out = (const float*)d_in[16];
    const float* b_out = (const float*)d_in[17];

    _Float16* wh = (_Float16*)d_ws;
    _Float16* xpad16  = wh + H_XPAD;
    _Float16* hpad16  = wh + H_HPAD;
    _Float16* apack1  = wh + H_APACK1;
    _Float16* apack2  = wh + H_APACK2;
    _Float16* apack3  = wh + H_APACK3;
    _Float16* a16     = wh + H_A16;
    _Float16* h16     = wh + H_H16;
    float* wsf  = (float*)((char*)d_ws + HALF_BYTES);
    float* qbuf = wsf + F_Q;
    float* kT   = wsf + F_KT;
    float* vT   = wsf + F_VT;
    float* gbuf = wsf + F_G;

    // zero padded-image borders (ws re-poisoned before every launch)
    hipMemsetAsync(wh, 0, HALF_BYTES >= 11075584 ? 11075584 : HALF_BYTES, stream);

    // weight packing (must rerun every call: ws poisoned)
    pack1_kernel<<<32256, 256, 0, stream>>>(wq_x, wq_h, wk_x, wk_h, wv_x, wv_h, wg_x, wg_h, apack1);
    pack_flat_kernel<<<1024, 256, 0, stream>>>(wg_a, apack2, 256, kKT2);
    pack_flat_kernel<<<256, 256, 0, stream>>>(w_out, apack3, 256, kKT3);

    // input staging
    padcvt_kernel<<<9216, 256, 0, stream>>>(h0, hpad16);
    conv1x1_pad_kernel<<<dim3(9, 16, kN), dim3(64, 4), 0, stream>>>(x, w_in, b_in, xpad16);

    // fused q/k/v/gates3x3 GEMM: M=1792, K=4608, N=576 x 16 batches
    gemm_kernel<0, 0><<<dim3(14, 9, kN), 256, 0, stream>>>(
        apack1, xpad16, hpad16, qbuf, kT, vT, gbuf, bv, kKT1, 0);

    // attention -> a16 [n][px][256]
    attn_kernel<<<dim3(9, kN * 8), 64, 0, stream>>>(qbuf, kT, vT, a16);

    // gates += wg_a . a + bg
    gemm_kernel<1, 1><<<dim3(8, 9, kN), 256, 0, stream>>>(
        apack2, a16, nullptr, nullptr, nullptr, nullptr, gbuf, bg, kKT2, 256);

    // LSTM -> h16 [n][px][256]
    lstm_kernel<<<dim3(9, 64, kN), dim3(64, 4), 0, stream>>>(gbuf, c0, h16);

    // out = w_out . h + b_out
    gemm_kernel<1, 2><<<dim3(2, 9, kN), 256, 0, stream>>>(
        apack3, h16, nullptr, (float*)d_out, nullptr, nullptr, nullptr, b_out, kKT3, 256);
}

// Round 3
// 695.015 us; speedup vs baseline: 11.7488x; 2.2288x over previous
//
#include <hip/hip_runtime.h>
#include <cstddef>

// ---- problem constants ----
constexpr int kN  = 16;
constexpr int kI  = 128;
constexpr int kHW = 24;
constexpr int kQ  = 576;    // 24*24
constexpr int kD  = 484;    // 22*22
constexpr int kDP = 512;    // padded d
constexpr int kPP = 676;    // 26*26 padded

// GEMM K-tiling
constexpr int kKT1 = 144;   // K1 = 4608
constexpr int kKT2 = 8;     // K2 = 256
constexpr int kKT3 = 8;     // K3 = 256

// ---- workspace layout ----
// half region (element offsets into _Float16*)
constexpr size_t H_XPAD   = 0;                          // [16][256][676]
constexpr size_t H_HPAD   = 2768896;                    // [16][256][676]
constexpr size_t H_APACK1 = 5537792;                    // 1792*4608 tiled
constexpr size_t H_APACK2 = 13795328;                   // 1024*256 tiled
constexpr size_t H_APACK3 = 14057472;                   // 256*256 tiled
constexpr size_t H_A16    = 14123008;                   // [16][576][256]
constexpr size_t H_H16    = 16482304;                   // [16][576][256]
constexpr size_t H_Q16C   = 18841600;                   // [16][256][576]  (c-major)
constexpr size_t H_KT16   = 21200896;                   // [128 head][512 d][32 c]
constexpr size_t H_VC16   = 23298048;                   // [128 head][32 c][512 d]
constexpr size_t HALF_ELEMS = 25395200;
constexpr size_t HALF_BYTES = HALF_ELEMS * 2;           // 50,790,400
// float region at d_ws + HALF_BYTES
constexpr size_t F_G = 0;                               // [16][1024][576]

using half4    = __attribute__((ext_vector_type(4))) _Float16;
using half8    = __attribute__((ext_vector_type(8))) _Float16;
using floatx16 = __attribute__((ext_vector_type(16))) float;

__device__ __forceinline__ float sigm(float x) { return 1.0f / (1.0f + __expf(-x)); }
__device__ __forceinline__ float tanh_f(float x) {
    float e = __expf(2.0f * fabsf(x));
    float r = 1.0f - 2.0f / (e + 1.0f);
    return copysignf(r, x);
}

__device__ __forceinline__ half8 ld8(const _Float16* p) {
    half4 lo = *(const half4*)p;
    half4 hi = *(const half4*)(p + 4);
    return __builtin_shufflevector(lo, hi, 0, 1, 2, 3, 4, 5, 6, 7);
}
__device__ __forceinline__ void st8(_Float16* p, half8 v) {
    *(half4*)p       = __builtin_shufflevector(v, v, 0, 1, 2, 3);
    *(half4*)(p + 4) = __builtin_shufflevector(v, v, 4, 5, 6, 7);
}

// ---------------- weight packing ----------------
// Apack layout: [mt][kt][128 rows][32 k] contiguous 4096-half tiles.
__global__ void pack1_kernel(const float* __restrict__ wq_x, const float* __restrict__ wq_h,
                             const float* __restrict__ wk_x, const float* __restrict__ wk_h,
                             const float* __restrict__ wv_x, const float* __restrict__ wv_h,
                             const float* __restrict__ wg_x, const float* __restrict__ wg_h,
                             _Float16* __restrict__ dst) {
    int pidx = blockIdx.x * 256 + threadIdx.x;
    int kcol = pidx & 31, mrow = (pidx >> 5) & 127, tile = pidx >> 12;
    int mt = tile / kKT1, kt = tile - mt * kKT1;
    int m = mt * 128 + mrow, k = kt * 32 + kcol;
    const float *s1, *s2; int mm;
    if (m < 256)      { s1 = wq_x; s2 = wq_h; mm = m; }
    else if (m < 512) { s1 = wk_x; s2 = wk_h; mm = m - 256; }
    else if (m < 768) { s1 = wv_x; s2 = wv_h; mm = m - 512; }
    else              { s1 = wg_x; s2 = wg_h; mm = m - 768; }
    float v = (k < 2304) ? s1[(size_t)mm * 2304 + k] : s2[(size_t)mm * 2304 + k - 2304];
    dst[pidx] = (_Float16)v;
}

__global__ void pack_flat_kernel(const float* __restrict__ src, _Float16* __restrict__ dst,
                                 int Ktot, int Ktiles) {
    int pidx = blockIdx.x * 256 + threadIdx.x;
    int kcol = pidx & 31, mrow = (pidx >> 5) & 127, tile = pidx >> 12;
    int mt = tile / Ktiles, kt = tile - mt * Ktiles;
    dst[pidx] = (_Float16)src[(size_t)(mt * 128 + mrow) * Ktot + kt * 32 + kcol];
}

// ---------------- input staging ----------------
__global__ void padcvt_kernel(const float* __restrict__ src, _Float16* __restrict__ dst) {
    int idx = blockIdx.x * 256 + threadIdx.x;    // 16*256*576 exactly
    int ch = idx / kQ, px = idx - ch * kQ;
    int y = px / kHW, x = px - y * kHW;
    dst[(size_t)ch * kPP + (y + 1) * 26 + (x + 1)] = (_Float16)src[idx];
}

__global__ void conv1x1_pad_kernel(const float* __restrict__ x, const float* __restrict__ w,
                                   const float* __restrict__ b, _Float16* __restrict__ out) {
    int px = blockIdx.x * 64 + threadIdx.x;
    int n = blockIdx.z;
    int oc0 = __builtin_amdgcn_readfirstlane(blockIdx.y * 16 + threadIdx.y * 4);
    const float* ip = x + (size_t)n * kI * kQ + px;
    float acc[4] = {0.f, 0.f, 0.f, 0.f};
    #pragma unroll 4
    for (int ic = 0; ic < kI; ++ic) {
        float xv = ip[(size_t)ic * kQ];
        #pragma unroll
        for (int j = 0; j < 4; ++j) acc[j] = fmaf(xv, w[(size_t)(oc0 + j) * kI + ic], acc[j]);
    }
    int y = px / kHW, xc = px - y * kHW;
    #pragma unroll
    for (int j = 0; j < 4; ++j)
        out[((size_t)n * 256 + oc0 + j) * kPP + (y + 1) * 26 + (xc + 1)] = (_Float16)(acc[j] + b[oc0 + j]);
}

// ---------------- fused MFMA GEMM ----------------
// BM=128, BN=64, BK=32; 256 threads = 4 waves.
// BMODE 0: B = on-the-fly im2col from two padded fp16 images
// BMODE 1: B = direct [n][576][Ktot] fp16
// EMODE 0: m<256 -> q16c [n][256 c][576 q] fp16
//          256..511 -> kT16 [head][512 d][32 c] fp16 (interior px only)
//          512..767 -> vC16 [head][32 c][512 d] fp16 (+bias)
//          768..1791 -> gbuf fp32 [n][1024][576]
// EMODE 1: gates += : pf[idx] = acc + pf[idx] + bias[m]
// EMODE 2: out = acc + bias[m] -> pf [n][256][576]
template<int BMODE, int EMODE>
__global__ __launch_bounds__(256)
void gemm_kernel(const _Float16* __restrict__ Apack,
                 const _Float16* __restrict__ B1, const _Float16* __restrict__ B2,
                 _Float16* __restrict__ q16, _Float16* __restrict__ k16,
                 _Float16* __restrict__ v16, float* __restrict__ pf,
                 const float* __restrict__ bias, int Ktiles, int Ktot) {
    __shared__ _Float16 As[128 * 36];
    __shared__ _Float16 Bs[64 * 36];
    const int tid = threadIdx.x;
    const int wv = tid >> 6, lane = tid & 63, l31 = lane & 31, hl = lane >> 5;
    const int mt = blockIdx.x, nt = blockIdx.y, n = blockIdx.z;

    floatx16 acc0 = {};
    floatx16 acc1 = {};

    const size_t Abase = (size_t)mt * Ktiles * 4096;
    const int arow = tid >> 1, ak = (tid & 1) * 16;
    const int px_l = tid >> 2, bg4 = (tid & 3) * 8;
    const int px = nt * 64 + px_l;
    const int by = px / kHW, bx = px - by * kHW;

    for (int kt = 0; kt < Ktiles; ++kt) {
        half8 a0 = *(const half8*)(Apack + Abase + (size_t)kt * 4096 + tid * 16);
        half8 a1 = *(const half8*)(Apack + Abase + (size_t)kt * 4096 + tid * 16 + 8);
        half8 bvv;
        if (BMODE == 0) {
            int kbase = kt * 32 + bg4;
            #pragma unroll
            for (int j = 0; j < 8; ++j) {
                int k = kbase + j;
                const _Float16* img = (k < 2304) ? B1 : B2;
                unsigned k2 = (k < 2304) ? k : k - 2304;
                unsigned ic = k2 / 9u;
                unsigned tap = k2 - ic * 9u;
                unsigned ty = tap / 3u, tx = tap - ty * 3u;
                bvv[j] = img[((size_t)n * 256 + ic) * kPP + (by + ty) * 26 + (bx + tx)];
            }
        } else {
            bvv = *(const half8*)(B1 + ((size_t)n * kQ + px) * Ktot + kt * 32 + bg4);
        }
        st8(&As[arow * 36 + ak], a0);
        st8(&As[arow * 36 + ak + 8], a1);
        st8(&Bs[px_l * 36 + bg4], bvv);
        __syncthreads();
        #pragma unroll
        for (int kk = 0; kk < 2; ++kk) {
            half8 af = ld8(&As[(wv * 32 + l31) * 36 + kk * 16 + hl * 8]);
            half8 b0 = ld8(&Bs[l31 * 36 + kk * 16 + hl * 8]);
            half8 b1 = ld8(&Bs[(32 + l31) * 36 + kk * 16 + hl * 8]);
            acc0 = __builtin_amdgcn_mfma_f32_32x32x16_f16(af, b0, acc0, 0, 0, 0);
            acc1 = __builtin_amdgcn_mfma_f32_32x32x16_f16(af, b1, acc1, 0, 0, 0);
        }
        __syncthreads();
    }

    // epilogue: C/D layout col=lane&31, row=(reg&3)+8*(reg>>2)+4*(lane>>5)
    const int mbase = mt * 128 + wv * 32;
    #pragma unroll
    for (int t2 = 0; t2 < 2; ++t2) {
        const floatx16& A = t2 ? acc1 : acc0;
        int pxe = nt * 64 + t2 * 32 + l31;
        #pragma unroll
        for (int r = 0; r < 16; ++r) {
            int rowi = (r & 3) + 8 * (r >> 2) + 4 * hl;
            int m = mbase + rowi;
            float val = A[r];
            if (EMODE == 0) {
                if (m < 256) {
                    q16[((size_t)n * 256 + m) * kQ + pxe] = (_Float16)val;
                } else if (m < 768) {
                    int ch = m & 255;
                    int yy = pxe / kHW, xx = pxe - yy * kHW;
                    if (yy >= 1 && yy <= 22 && xx >= 1 && xx <= 22) {
                        int d = (yy - 1) * 22 + (xx - 1);
                        int head = n * 8 + (ch >> 5);
                        if (m < 512)
                            k16[((size_t)head * kDP + d) * 32 + (ch & 31)] = (_Float16)val;
                        else
                            v16[((size_t)head * 32 + (ch & 31)) * kDP + d] = (_Float16)(val + bias[ch]);
                    }
                } else {
                    pf[((size_t)n * 1024 + (m - 768)) * kQ + pxe] = val;
                }
            } else if (EMODE == 1) {
                size_t o = ((size_t)n * 1024 + m) * kQ + pxe;
                pf[o] = val + pf[o] + bias[m];
            } else {
                pf[((size_t)n * 256 + m) * kQ + pxe] = val + bias[m];
            }
        }
    }
}

// ---------------- MFMA flash attention ----------------
// grid (9, 128), block 128 = 2 waves; wave handles one 32-row q-tile of
// one (n,head). S^T tile [32 d][32 q] per d-tile via 2 mfma; online softmax
// on C-layout regs; P -> B-operand via shfl_xor(32) half-swap; PV via 2 mfma.
__global__ __launch_bounds__(128)
void attn_kernel(const _Float16* __restrict__ q16c, const _Float16* __restrict__ kT16,
                 const _Float16* __restrict__ vC16, _Float16* __restrict__ a16) {
    const int lane = threadIdx.x & 63;
    const int wv   = threadIdx.x >> 6;
    const int l31 = lane & 31, hl = lane >> 5;
    const int head = blockIdx.y;            // n*8 + hd
    const int n = head >> 3, hd = head & 7;
    const int qt = blockIdx.x * 2 + wv;     // 0..17
    const int q0 = qt * 32;

    // q B-frags: B[k=c][n=q], c = chunk*16 + hl*8 + j
    half8 qf0, qf1;
    {
        const _Float16* qb = q16c + ((size_t)n * 256 + hd * 32 + hl * 8) * kQ + q0 + l31;
        #pragma unroll
        for (int j = 0; j < 8; ++j) {
            qf0[j] = qb[(size_t)j * kQ];
            qf1[j] = qb[(size_t)(16 + j) * kQ];
        }
    }

    const _Float16* kbase0 = kT16 + ((size_t)head * kDP + l31) * 32 + hl * 8;
    const _Float16* vbase0 = vC16 + ((size_t)head * 32 + l31) * kDP + hl * 8;

    floatx16 acc = {};
    float m_run = -1e30f, l_run = 0.f;

    half8 kf0 = ld8(kbase0);
    half8 kf1 = ld8(kbase0 + 16);

    for (int dt = 0; dt < 16; ++dt) {
        const int d0 = dt * 32;
        floatx16 S = {};
        S = __builtin_amdgcn_mfma_f32_32x32x16_f16(kf0, qf0, S, 0, 0, 0);
        S = __builtin_amdgcn_mfma_f32_32x32x16_f16(kf1, qf1, S, 0, 0, 0);

        // prefetch v(dt) and k(dt+1)
        half8 vf0 = ld8(vbase0 + d0);
        half8 vf1 = ld8(vbase0 + d0 + 16);
        if (dt < 15) {
            kf0 = ld8(kbase0 + (size_t)(d0 + 32) * 32);
            kf1 = ld8(kbase0 + (size_t)(d0 + 32) * 32 + 16);
        }

        // mask pad rows (d >= 484) on last tile: valid only hl==0 && r<4
        if (dt == 15) {
            #pragma unroll
            for (int r = 0; r < 16; ++r)
                if (!(hl == 0 && r < 4)) S[r] = -1e30f;
        }

        // online softmax (per q-col; lanes l, l^32 share col)
        float tmax = S[0];
        #pragma unroll
        for (int r = 1; r < 16; ++r) tmax = fmaxf(tmax, S[r]);
        tmax = fmaxf(tmax, __shfl_xor(tmax, 32));
        float mnew = fmaxf(m_run, tmax);
        float f = __expf(m_run - mnew);
        float p[16], psum = 0.f;
        #pragma unroll
        for (int r = 0; r < 16; ++r) { p[r] = __expf(S[r] - mnew); psum += p[r]; }
        psum += __shfl_xor(psum, 32);
        l_run = f * l_run + psum;
        #pragma unroll
        for (int r = 0; r < 16; ++r) acc[r] *= f;
        m_run = mnew;

        // P (C-layout) -> B-operand frags via half-swap
        float other[16];
        #pragma unroll
        for (int r = 0; r < 16; ++r) other[r] = __shfl_xor(p[r], 32);
        half8 pf0, pf1;
        #pragma unroll
        for (int t = 0; t < 4; ++t) {
            pf0[t]     = (_Float16)(hl ? other[4 + t]  : p[t]);
            pf0[4 + t] = (_Float16)(hl ? p[4 + t]      : other[t]);
            pf1[t]     = (_Float16)(hl ? other[12 + t] : p[8 + t]);
            pf1[4 + t] = (_Float16)(hl ? p[12 + t]     : other[8 + t]);
        }

        acc = __builtin_amdgcn_mfma_f32_32x32x16_f16(vf0, pf0, acc, 0, 0, 0);
        acc = __builtin_amdgcn_mfma_f32_32x32x16_f16(vf1, pf1, acc, 0, 0, 0);
    }

    // epilogue: out^T[c][q], c = rowidx, q = l31 -> a16 [n][q][256]
    float inv = 1.f / l_run;
    _Float16* ap = a16 + ((size_t)n * kQ + q0 + l31) * 256 + hd * 32;
    #pragma unroll
    for (int r = 0; r < 16; ++r) {
        int c = (r & 3) + 8 * (r >> 2) + 4 * hl;
        ap[c] = (_Float16)(acc[r] * inv);
    }
}

// ---------------- LSTM elementwise ----------------
__global__ void lstm_kernel(const float* __restrict__ gates, const float* __restrict__ c0,
                            _Float16* __restrict__ h16) {
    int px = blockIdx.x * 64 + threadIdx.x;
    int r = blockIdx.y * 4 + threadIdx.y;
    int n = blockIdx.z;
    size_t base = (size_t)n * 1024 * kQ + px;
    float iv = gates[base + (size_t)r * kQ];
    float fv = gates[base + (size_t)(256 + r) * kQ];
    float gv = gates[base + (size_t)(512 + r) * kQ];
    float ov = gates[base + (size_t)(768 + r) * kQ];
    float c = sigm(fv) * c0[((size_t)n * 256 + r) * kQ + px] + sigm(iv) * tanh_f(gv);
    float h = sigm(ov) * tanh_f(c);
    h16[((size_t)n * kQ + px) * 256 + r] = (_Float16)h;
}

extern "C" void kernel_launch(void* const* d_in, const int* in_sizes, int n_in,
                              void* d_out, int out_size, void* d_ws, size_t ws_size,
                              hipStream_t stream) {
    (void)in_sizes; (void)n_in; (void)out_size; (void)ws_size;
    const float* x     = (const float*)d_in[0];
    const float* h0    = (const float*)d_in[1];
    const float* c0    = (const float*)d_in[2];
    const float* w_in  = (const float*)d_in[3];
    const float* b_in  = (const float*)d_in[4];
    const float* wq_x  = (const float*)d_in[5];
    const float* wq_h  = (const float*)d_in[6];
    const float* wk_x  = (const float*)d_in[7];
    const float* wk_h  = (const float*)d_in[8];
    const float* wv_x  = (const float*)d_in[9];
    const float* wv_h  = (const float*)d_in[10];
    const float* bv    = (const float*)d_in[11];
    const float* wg_a  = (const float*)d_in[12];
    const float* bg    = (const float*)d_in[13];
    const float* wg_x  = (const float*)d_in[14];
    const float* wg_h  = (const float*)d_in[15];
    const float* w_out = (const float*)d_in[16];
    const float* b_out = (const float*)d_in[17];

    _Float16* wh = (_Float16*)d_ws;
    _Float16* xpad16  = wh + H_XPAD;
    _Float16* hpad16  = wh + H_HPAD;
    _Float16* apack1  = wh + H_APACK1;
    _Float16* apack2  = wh + H_APACK2;
    _Float16* apack3  = wh + H_APACK3;
    _Float16* a16     = wh + H_A16;
    _Float16* h16     = wh + H_H16;
    _Float16* q16c    = wh + H_Q16C;
    _Float16* kT16    = wh + H_KT16;
    _Float16* vC16    = wh + H_VC16;
    float* gbuf = (float*)((char*)d_ws + HALF_BYTES) + F_G;

    // zero padded-image borders (ws re-poisoned each launch)
    hipMemsetAsync(wh, 0, 11075584, stream);

    // weight packing
    pack1_kernel<<<32256, 256, 0, stream>>>(wq_x, wq_h, wk_x, wk_h, wv_x, wv_h, wg_x, wg_h, apack1);
    pack_flat_kernel<<<1024, 256, 0, stream>>>(wg_a, apack2, 256, kKT2);
    pack_flat_kernel<<<256, 256, 0, stream>>>(w_out, apack3, 256, kKT3);

    // input staging
    padcvt_kernel<<<9216, 256, 0, stream>>>(h0, hpad16);
    conv1x1_pad_kernel<<<dim3(9, 16, kN), dim3(64, 4), 0, stream>>>(x, w_in, b_in, xpad16);

    // fused q/k/v/gates3x3 GEMM: M=1792, K=4608, N=576 x 16 batches
    gemm_kernel<0, 0><<<dim3(14, 9, kN), 256, 0, stream>>>(
        apack1, xpad16, hpad16, q16c, kT16, vC16, gbuf, bv, kKT1, 0);

    // MFMA flash attention -> a16 [n][px][256]
    attn_kernel<<<dim3(9, 128), 128, 0, stream>>>(q16c, kT16, vC16, a16);

    // gates += wg_a . a + bg
    gemm_kernel<1, 1><<<dim3(8, 9, kN), 256, 0, stream>>>(
        apack2, a16, nullptr, nullptr, nullptr, nullptr, gbuf, bg, kKT2, 256);

    // LSTM -> h16 [n][px][256]
    lstm_kernel<<<dim3(9, 64, kN), dim3(64, 4), 0, stream>>>(gbuf, c0, h16);

    // out = w_out . h + b_out
    gemm_kernel<1, 2><<<dim3(2, 9, kN), 256, 0, stream>>>(
        apack3, h16, nullptr, nullptr, nullptr, nullptr, (float*)d_out, b_out, kKT3, 256);
}

// Round 4
// 457.284 us; speedup vs baseline: 17.8566x; 1.5199x over previous
//
#include <hip/hip_runtime.h>
#include <cstddef>

// ---- problem constants ----
constexpr int kN  = 16;
constexpr int kI  = 128;
constexpr int kHW = 24;
constexpr int kQ  = 576;    // 24*24
constexpr int kD  = 484;    // 22*22
constexpr int kDP = 512;    // padded d
constexpr int kPP = 676;    // 26*26 padded

// GEMM K-tiling
constexpr int kKT1 = 144;   // K1 = 4608 (= 2 src * 9 tap * 256 ic)
constexpr int kKT2 = 8;     // K2 = 256
constexpr int kKT3 = 8;     // K3 = 256

// ---- workspace layout ----
// half region (element offsets into _Float16*)
constexpr size_t H_XPAD   = 0;                          // [16][26][26][256] NHWC
constexpr size_t H_HPAD   = 2768896;                    // [16][26][26][256] NHWC
constexpr size_t H_APACK1 = 5537792;                    // 1792*4608 frag-tiled
constexpr size_t H_APACK2 = 13795328;                   // 1024*256 frag-tiled
constexpr size_t H_APACK3 = 14057472;                   // 256*256 frag-tiled
constexpr size_t H_A16    = 14123008;                   // [16][576][256]
constexpr size_t H_H16    = 16482304;                   // [16][576][256]
constexpr size_t H_Q16C   = 18841600;                   // [16][256][576]  (c-major)
constexpr size_t H_KT16   = 21200896;                   // [128 head][512 d][32 c]
constexpr size_t H_VC16   = 23298048;                   // [128 head][32 c][512 d]
constexpr size_t HALF_ELEMS = 25395200;
constexpr size_t HALF_BYTES = HALF_ELEMS * 2;           // 50,790,400
// float region at d_ws + HALF_BYTES
constexpr size_t F_G = 0;                               // [16][1024][576]

using half4    = __attribute__((ext_vector_type(4))) _Float16;
using half8    = __attribute__((ext_vector_type(8))) _Float16;
using floatx16 = __attribute__((ext_vector_type(16))) float;

__device__ __forceinline__ float sigm(float x) { return 1.0f / (1.0f + __expf(-x)); }
__device__ __forceinline__ float tanh_f(float x) {
    float e = __expf(2.0f * fabsf(x));
    float r = 1.0f - 2.0f / (e + 1.0f);
    return copysignf(r, x);
}

// 16B-aligned vector load/store (emits b128 ops)
__device__ __forceinline__ half8 LD8(const _Float16* p) { return *(const half8*)p; }
__device__ __forceinline__ void ST8(_Float16* p, half8 v) { *(half8*)p = v; }

// ---------------- weight packing ----------------
// Apack layout: [mt][kt][kk(2)][hl(2)][row(128)][j(8)] — exact A-fragment order.
// K-order for gemm1: k = src*2304 + tap*256 + ic  (maps to source ic*9+tap)
__global__ void pack1_kernel(const float* __restrict__ wq_x, const float* __restrict__ wq_h,
                             const float* __restrict__ wk_x, const float* __restrict__ wk_h,
                             const float* __restrict__ wv_x, const float* __restrict__ wv_h,
                             const float* __restrict__ wg_x, const float* __restrict__ wg_h,
                             _Float16* __restrict__ dst) {
    int pidx = blockIdx.x * 256 + threadIdx.x;
    int j = pidx & 7, row = (pidx >> 3) & 127, hl = (pidx >> 10) & 1, kk = (pidx >> 11) & 1;
    int tile = pidx >> 12;
    int mt = tile / kKT1, kt = tile - mt * kKT1;
    int m = mt * 128 + row;
    int k = kt * 32 + kk * 16 + hl * 8 + j;
    int srcs = (k >= 2304) ? 1 : 0;
    int r = k - srcs * 2304;
    int tap = r >> 8, ic = r & 255;
    const float *s1, *s2; int mm;
    if (m < 256)      { s1 = wq_x; s2 = wq_h; mm = m; }
    else if (m < 512) { s1 = wk_x; s2 = wk_h; mm = m - 256; }
    else if (m < 768) { s1 = wv_x; s2 = wv_h; mm = m - 512; }
    else              { s1 = wg_x; s2 = wg_h; mm = m - 768; }
    const float* sp = srcs ? s2 : s1;
    dst[pidx] = (_Float16)sp[(size_t)mm * 2304 + ic * 9 + tap];
}

__global__ void pack_flat_kernel(const float* __restrict__ src, _Float16* __restrict__ dst,
                                 int Ktot, int Ktiles) {
    int pidx = blockIdx.x * 256 + threadIdx.x;
    int j = pidx & 7, row = (pidx >> 3) & 127, hl = (pidx >> 10) & 1, kk = (pidx >> 11) & 1;
    int tile = pidx >> 12;
    int mt = tile / Ktiles, kt = tile - mt * Ktiles;
    int m = mt * 128 + row;
    int k = kt * 32 + kk * 16 + hl * 8 + j;
    dst[pidx] = (_Float16)src[(size_t)m * Ktot + k];
}

// ---------------- input staging ----------------
// h0 [n][256][576] fp32 -> NHWC fp16 padded [n][26][26][256] (borders pre-zeroed)
__global__ void pad_nhwc_kernel(const float* __restrict__ src, _Float16* __restrict__ dst) {
    __shared__ float tile[32][65];
    int pxt = blockIdx.x, ict = blockIdx.y, n = blockIdx.z;
    int tid = threadIdx.x;
    {
        int icl = tid >> 6, pxl = tid & 63;
        #pragma unroll
        for (int rep = 0; rep < 8; ++rep) {
            int ic = ict * 32 + rep * 4 + icl;
            tile[rep * 4 + icl][pxl] = src[((size_t)n * 256 + ic) * kQ + pxt * 64 + pxl];
        }
    }
    __syncthreads();
    {
        int icl = tid & 31, pxl0 = tid >> 5;
        #pragma unroll
        for (int rep = 0; rep < 8; ++rep) {
            int pxl = rep * 8 + pxl0;
            int px = pxt * 64 + pxl;
            int y = px / kHW, x = px - y * kHW;
            dst[((size_t)n * kPP + (size_t)(y + 1) * 26 + (x + 1)) * 256 + ict * 32 + icl] =
                (_Float16)tile[icl][pxl];
        }
    }
}

// xin = 1x1 conv(x, w_in)+b_in -> NHWC fp16 padded
__global__ void conv1x1_pad_kernel(const float* __restrict__ x, const float* __restrict__ w,
                                   const float* __restrict__ b, _Float16* __restrict__ out) {
    int px = blockIdx.x * 64 + threadIdx.x;
    int n = blockIdx.z;
    int oc0 = __builtin_amdgcn_readfirstlane(blockIdx.y * 16 + threadIdx.y * 4);
    const float* ip = x + (size_t)n * kI * kQ + px;
    float acc[4] = {0.f, 0.f, 0.f, 0.f};
    #pragma unroll 4
    for (int ic = 0; ic < kI; ++ic) {
        float xv = ip[(size_t)ic * kQ];
        #pragma unroll
        for (int j = 0; j < 4; ++j) acc[j] = fmaf(xv, w[(size_t)(oc0 + j) * kI + ic], acc[j]);
    }
    int y = px / kHW, xc = px - y * kHW;
    _Float16* op = out + ((size_t)n * kPP + (size_t)(y + 1) * 26 + (xc + 1)) * 256 + oc0;
    #pragma unroll
    for (int j = 0; j < 4; ++j) op[j] = (_Float16)(acc[j] + b[oc0 + j]);
}

// ---------------- fused MFMA GEMM ----------------
// BM=128, BN=64, BK=32; 256 threads = 4 waves; wave wv: rows wv*32..+31.
// A: direct global fragment loads from packed layout (no LDS).
// B: one half8/thread -> swizzled LDS (64B rows, chunk^=(row>>1)&3), b128 all the way.
// BMODE 0: B = on-the-fly im2col from two NHWC fp16 images, K=(src,tap,ic)
// BMODE 1: B = direct [n][576][Ktot] fp16 (channel-last)
// EMODE 0: m<256 -> q16c; 256..511 -> kT16; 512..767 -> vC16(+bias); 768.. -> gbuf
// EMODE 1: gates += : pf[idx] = acc + pf[idx] + bias[m]
// EMODE 2: out = acc + bias[m] -> pf
template<int BMODE, int EMODE>
__global__ __launch_bounds__(256)
void gemm_kernel(const _Float16* __restrict__ Apack,
                 const _Float16* __restrict__ B1, const _Float16* __restrict__ B2,
                 _Float16* __restrict__ q16, _Float16* __restrict__ k16,
                 _Float16* __restrict__ v16, float* __restrict__ pf,
                 const float* __restrict__ bias, int Ktiles, int Ktot) {
    __shared__ _Float16 Bs[2][2048];
    const int tid = threadIdx.x;
    const int wv = tid >> 6, lane = tid & 63, l31 = lane & 31, hl = lane >> 5;
    const int mt = blockIdx.x, nt = blockIdx.y, n = blockIdx.z;

    floatx16 acc0 = {};
    floatx16 acc1 = {};

    const _Float16* aptr = Apack + (size_t)mt * Ktiles * 4096
                         + (size_t)hl * 1024 + (size_t)(wv * 32 + l31) * 8;

    const int px_l = tid >> 2, bc = tid & 3;
    const int px = nt * 64 + px_l;
    const int by = px / kHW, bx = px - by * kHW;

    // swizzled LDS offsets
    const int wofs = px_l * 32 + ((bc ^ ((px_l >> 1) & 3)) << 3);
    const int sw = (l31 >> 1) & 3;
    const int r00 = l31 * 32        + ((hl ^ sw) << 3);        // kk=0, cols 0..31
    const int r01 = (32 + l31) * 32 + ((hl ^ sw) << 3);        // kk=0, cols 32..63
    const int r10 = l31 * 32        + (((2 + hl) ^ sw) << 3);  // kk=1
    const int r11 = (32 + l31) * 32 + (((2 + hl) ^ sw) << 3);

    for (int kt = 0; kt < Ktiles; ++kt) {
        const _Float16* bp;
        if (BMODE == 0) {
            int srcs = (kt >= 72) ? 1 : 0;
            int t2 = kt - srcs * 72;
            int tap = t2 >> 3, ict = t2 & 7;
            int ty = (tap * 11) >> 5;          // tap/3 for 0..8
            int tx = tap - ty * 3;
            const _Float16* img = srcs ? B2 : B1;
            bp = img + ((size_t)n * kPP + (size_t)(by + ty) * 26 + (bx + tx)) * 256
                     + ict * 32 + bc * 8;
        } else {
            bp = B1 + ((size_t)n * kQ + px) * Ktot + kt * 32 + bc * 8;
        }
        half8 bv = LD8(bp);
        half8 a0 = LD8(aptr);
        half8 a1 = LD8(aptr + 2048);
        aptr += 4096;
        ST8(&Bs[kt & 1][wofs], bv);
        __syncthreads();
        const _Float16* bb = Bs[kt & 1];
        half8 b00 = LD8(bb + r00);
        half8 b01 = LD8(bb + r01);
        half8 b10 = LD8(bb + r10);
        half8 b11 = LD8(bb + r11);
        acc0 = __builtin_amdgcn_mfma_f32_32x32x16_f16(a0, b00, acc0, 0, 0, 0);
        acc1 = __builtin_amdgcn_mfma_f32_32x32x16_f16(a0, b01, acc1, 0, 0, 0);
        acc0 = __builtin_amdgcn_mfma_f32_32x32x16_f16(a1, b10, acc0, 0, 0, 0);
        acc1 = __builtin_amdgcn_mfma_f32_32x32x16_f16(a1, b11, acc1, 0, 0, 0);
    }

    // epilogue: C/D layout col=lane&31, row=(reg&3)+8*(reg>>2)+4*(lane>>5)
    const int mbase = mt * 128 + wv * 32;
    #pragma unroll
    for (int t2 = 0; t2 < 2; ++t2) {
        const floatx16& A = t2 ? acc1 : acc0;
        int pxe = nt * 64 + t2 * 32 + l31;
        #pragma unroll
        for (int r = 0; r < 16; ++r) {
            int rowi = (r & 3) + 8 * (r >> 2) + 4 * hl;
            int m = mbase + rowi;
            float val = A[r];
            if (EMODE == 0) {
                if (m < 256) {
                    q16[((size_t)n * 256 + m) * kQ + pxe] = (_Float16)val;
                } else if (m < 768) {
                    int ch = m & 255;
                    int yy = pxe / kHW, xx = pxe - yy * kHW;
                    if (yy >= 1 && yy <= 22 && xx >= 1 && xx <= 22) {
                        int d = (yy - 1) * 22 + (xx - 1);
                        int head = n * 8 + (ch >> 5);
                        if (m < 512)
                            k16[((size_t)head * kDP + d) * 32 + (ch & 31)] = (_Float16)val;
                        else
                            v16[((size_t)head * 32 + (ch & 31)) * kDP + d] = (_Float16)(val + bias[ch]);
                    }
                } else {
                    pf[((size_t)n * 1024 + (m - 768)) * kQ + pxe] = val;
                }
            } else if (EMODE == 1) {
                size_t o = ((size_t)n * 1024 + m) * kQ + pxe;
                pf[o] = val + pf[o] + bias[m];
            } else {
                pf[((size_t)n * 256 + m) * kQ + pxe] = val + bias[m];
            }
        }
    }
}

// ---------------- MFMA flash attention ----------------
__global__ __launch_bounds__(128)
void attn_kernel(const _Float16* __restrict__ q16c, const _Float16* __restrict__ kT16,
                 const _Float16* __restrict__ vC16, _Float16* __restrict__ a16) {
    const int lane = threadIdx.x & 63;
    const int wv   = threadIdx.x >> 6;
    const int l31 = lane & 31, hl = lane >> 5;
    const int head = blockIdx.y;            // n*8 + hd
    const int n = head >> 3, hd = head & 7;
    const int qt = blockIdx.x * 2 + wv;     // 0..17
    const int q0 = qt * 32;

    half8 qf0, qf1;
    {
        const _Float16* qb = q16c + ((size_t)n * 256 + hd * 32 + hl * 8) * kQ + q0 + l31;
        #pragma unroll
        for (int j = 0; j < 8; ++j) {
            qf0[j] = qb[(size_t)j * kQ];
            qf1[j] = qb[(size_t)(16 + j) * kQ];
        }
    }

    const _Float16* kbase0 = kT16 + ((size_t)head * kDP + l31) * 32 + hl * 8;
    const _Float16* vbase0 = vC16 + ((size_t)head * 32 + l31) * kDP + hl * 8;

    floatx16 acc = {};
    float m_run = -1e30f, l_run = 0.f;

    half8 kf0 = LD8(kbase0);
    half8 kf1 = LD8(kbase0 + 16);

    for (int dt = 0; dt < 16; ++dt) {
        const int d0 = dt * 32;
        floatx16 S = {};
        S = __builtin_amdgcn_mfma_f32_32x32x16_f16(kf0, qf0, S, 0, 0, 0);
        S = __builtin_amdgcn_mfma_f32_32x32x16_f16(kf1, qf1, S, 0, 0, 0);

        half8 vf0 = LD8(vbase0 + d0);
        half8 vf1 = LD8(vbase0 + d0 + 16);
        if (dt < 15) {
            kf0 = LD8(kbase0 + (size_t)(d0 + 32) * 32);
            kf1 = LD8(kbase0 + (size_t)(d0 + 32) * 32 + 16);
        }

        if (dt == 15) {
            #pragma unroll
            for (int r = 0; r < 16; ++r)
                if (!(hl == 0 && r < 4)) S[r] = -1e30f;
        }

        float tmax = S[0];
        #pragma unroll
        for (int r = 1; r < 16; ++r) tmax = fmaxf(tmax, S[r]);
        tmax = fmaxf(tmax, __shfl_xor(tmax, 32));
        float mnew = fmaxf(m_run, tmax);
        float f = __expf(m_run - mnew);
        float p[16], psum = 0.f;
        #pragma unroll
        for (int r = 0; r < 16; ++r) { p[r] = __expf(S[r] - mnew); psum += p[r]; }
        psum += __shfl_xor(psum, 32);
        l_run = f * l_run + psum;
        #pragma unroll
        for (int r = 0; r < 16; ++r) acc[r] *= f;
        m_run = mnew;

        float other[16];
        #pragma unroll
        for (int r = 0; r < 16; ++r) other[r] = __shfl_xor(p[r], 32);
        half8 pf0, pf1;
        #pragma unroll
        for (int t = 0; t < 4; ++t) {
            pf0[t]     = (_Float16)(hl ? other[4 + t]  : p[t]);
            pf0[4 + t] = (_Float16)(hl ? p[4 + t]      : other[t]);
            pf1[t]     = (_Float16)(hl ? other[12 + t] : p[8 + t]);
            pf1[4 + t] = (_Float16)(hl ? p[12 + t]     : other[8 + t]);
        }

        acc = __builtin_amdgcn_mfma_f32_32x32x16_f16(vf0, pf0, acc, 0, 0, 0);
        acc = __builtin_amdgcn_mfma_f32_32x32x16_f16(vf1, pf1, acc, 0, 0, 0);
    }

    float inv = 1.f / l_run;
    _Float16* ap = a16 + ((size_t)n * kQ + q0 + l31) * 256 + hd * 32;
    #pragma unroll
    for (int r = 0; r < 16; ++r) {
        int c = (r & 3) + 8 * (r >> 2) + 4 * hl;
        ap[c] = (_Float16)(acc[r] * inv);
    }
}

// ---------------- LSTM elementwise ----------------
__global__ void lstm_kernel(const float* __restrict__ gates, const float* __restrict__ c0,
                            _Float16* __restrict__ h16) {
    int px = blockIdx.x * 64 + threadIdx.x;
    int r = blockIdx.y * 4 + threadIdx.y;
    int n = blockIdx.z;
    size_t base = (size_t)n * 1024 * kQ + px;
    float iv = gates[base + (size_t)r * kQ];
    float fv = gates[base + (size_t)(256 + r) * kQ];
    float gv = gates[base + (size_t)(512 + r) * kQ];
    float ov = gates[base + (size_t)(768 + r) * kQ];
    float c = sigm(fv) * c0[((size_t)n * 256 + r) * kQ + px] + sigm(iv) * tanh_f(gv);
    float h = sigm(ov) * tanh_f(c);
    h16[((size_t)n * kQ + px) * 256 + r] = (_Float16)h;
}

extern "C" void kernel_launch(void* const* d_in, const int* in_sizes, int n_in,
                              void* d_out, int out_size, void* d_ws, size_t ws_size,
                              hipStream_t stream) {
    (void)in_sizes; (void)n_in; (void)out_size; (void)ws_size;
    const float* x     = (const float*)d_in[0];
    const float* h0    = (const float*)d_in[1];
    const float* c0    = (const float*)d_in[2];
    const float* w_in  = (const float*)d_in[3];
    const float* b_in  = (const float*)d_in[4];
    const float* wq_x  = (const float*)d_in[5];
    const float* wq_h  = (const float*)d_in[6];
    const float* wk_x  = (const float*)d_in[7];
    const float* wk_h  = (const float*)d_in[8];
    const float* wv_x  = (const float*)d_in[9];
    const float* wv_h  = (const float*)d_in[10];
    const float* bv    = (const float*)d_in[11];
    const float* wg_a  = (const float*)d_in[12];
    const float* bg    = (const float*)d_in[13];
    const float* wg_x  = (const float*)d_in[14];
    const float* wg_h  = (const float*)d_in[15];
    const float* w_out = (const float*)d_in[16];
    const float* b_out = (const float*)d_in[17];

    _Float16* wh = (_Float16*)d_ws;
    _Float16* xpad16  = wh + H_XPAD;
    _Float16* hpad16  = wh + H_HPAD;
    _Float16* apack1  = wh + H_APACK1;
    _Float16* apack2  = wh + H_APACK2;
    _Float16* apack3  = wh + H_APACK3;
    _Float16* a16     = wh + H_A16;
    _Float16* h16     = wh + H_H16;
    _Float16* q16c    = wh + H_Q16C;
    _Float16* kT16    = wh + H_KT16;
    _Float16* vC16    = wh + H_VC16;
    float* gbuf = (float*)((char*)d_ws + HALF_BYTES) + F_G;

    // zero NHWC image borders (ws re-poisoned each launch)
    hipMemsetAsync(wh, 0, 11075584, stream);

    // weight packing (fragment-order)
    pack1_kernel<<<32256, 256, 0, stream>>>(wq_x, wq_h, wk_x, wk_h, wv_x, wv_h, wg_x, wg_h, apack1);
    pack_flat_kernel<<<1024, 256, 0, stream>>>(wg_a, apack2, 256, kKT2);
    pack_flat_kernel<<<256, 256, 0, stream>>>(w_out, apack3, 256, kKT3);

    // input staging (NHWC fp16)
    pad_nhwc_kernel<<<dim3(9, 8, kN), 256, 0, stream>>>(h0, hpad16);
    conv1x1_pad_kernel<<<dim3(9, 16, kN), dim3(64, 4), 0, stream>>>(x, w_in, b_in, xpad16);

    // fused q/k/v/gates3x3 GEMM: M=1792, K=4608, N=576 x 16 batches
    gemm_kernel<0, 0><<<dim3(14, 9, kN), 256, 0, stream>>>(
        apack1, xpad16, hpad16, q16c, kT16, vC16, gbuf, bv, kKT1, 0);

    // MFMA flash attention -> a16 [n][px][256]
    attn_kernel<<<dim3(9, 128), 128, 0, stream>>>(q16c, kT16, vC16, a16);

    // gates += wg_a . a + bg
    gemm_kernel<1, 1><<<dim3(8, 9, kN), 256, 0, stream>>>(
        apack2, a16, nullptr, nullptr, nullptr, nullptr, gbuf, bg, kKT2, 256);

    // LSTM -> h16 [n][px][256]
    lstm_kernel<<<dim3(9, 64, kN), dim3(64, 4), 0, stream>>>(gbuf, c0, h16);

    // out = w_out . h + b_out
    gemm_kernel<1, 2><<<dim3(2, 9, kN), 256, 0, stream>>>(
        apack3, h16, nullptr, nullptr, nullptr, nullptr, (float*)d_out, b_out, kKT3, 256);
}